// Round 1
// baseline (20592.287 us; speedup 1.0000x reference)
//
#include <hip/hip_runtime.h>
#include <hip/hip_bf16.h>

// MLA forward, round 1: correctness-first f32 implementation.
// B=2 S=2048 D=2048 H=16 NOPE=128 ROPE=64 V=128 C=512
#define B_ 2
#define S_ 2048
#define D_ 2048
#define H_ 16

// ---------------------------------------------------------------------------
// Generic f32 GEMM:  C[M,N] = A[M,K] @ B[N,K]^T   (both row-major, K-contig)
// Requires M%64==0, N%64==0, K%16==0 (true for all three uses).
// 64x64 tile, BK=16, 256 threads, 4x4 accum per thread.
// ---------------------------------------------------------------------------
__global__ __launch_bounds__(256) void gemm_nt(const float* __restrict__ A,
                                               const float* __restrict__ Bm,
                                               float* __restrict__ Cm,
                                               int M, int N, int K,
                                               int lda, int ldb, int ldc)
{
    __shared__ float As[16][68];   // [k][m], +4 pad keeps float4 alignment, breaks conflicts
    __shared__ float Bs[16][68];   // [k][n]
    const int tid = threadIdx.x;
    const int m0 = blockIdx.y * 64, n0 = blockIdx.x * 64;
    const int lr = tid >> 2;          // 0..63 row within tile
    const int lc = (tid & 3) << 2;    // 0,4,8,12 k-offset
    const int ty = tid >> 4, tx = tid & 15;
    const float* Ag = A  + (m0 + lr) * lda + lc;
    const float* Bg = Bm + (n0 + lr) * ldb + lc;

    float acc[4][4];
#pragma unroll
    for (int i = 0; i < 4; i++)
#pragma unroll
        for (int j = 0; j < 4; j++) acc[i][j] = 0.f;

    for (int k0 = 0; k0 < K; k0 += 16) {
        float4 av = *(const float4*)(Ag + k0);
        float4 bv = *(const float4*)(Bg + k0);
        __syncthreads();
        As[lc+0][lr] = av.x; As[lc+1][lr] = av.y; As[lc+2][lr] = av.z; As[lc+3][lr] = av.w;
        Bs[lc+0][lr] = bv.x; Bs[lc+1][lr] = bv.y; Bs[lc+2][lr] = bv.z; Bs[lc+3][lr] = bv.w;
        __syncthreads();
#pragma unroll
        for (int kk = 0; kk < 16; kk++) {
            float4 a = *(const float4*)&As[kk][ty*4];
            float4 b = *(const float4*)&Bs[kk][tx*4];
            acc[0][0] += a.x*b.x; acc[0][1] += a.x*b.y; acc[0][2] += a.x*b.z; acc[0][3] += a.x*b.w;
            acc[1][0] += a.y*b.x; acc[1][1] += a.y*b.y; acc[1][2] += a.y*b.z; acc[1][3] += a.y*b.w;
            acc[2][0] += a.z*b.x; acc[2][1] += a.z*b.y; acc[2][2] += a.z*b.z; acc[2][3] += a.z*b.w;
            acc[3][0] += a.w*b.x; acc[3][1] += a.w*b.y; acc[3][2] += a.w*b.z; acc[3][3] += a.w*b.w;
        }
    }
#pragma unroll
    for (int i = 0; i < 4; i++) {
        float4 r; r.x = acc[i][0]; r.y = acc[i][1]; r.z = acc[i][2]; r.w = acc[i][3];
        *(float4*)(Cm + (m0 + ty*4 + i) * ldc + n0 + tx*4) = r;
    }
}

// ---------------------------------------------------------------------------
// kvr (BS x 576) -> kvn (BS x 512, rmsnorm * w), kpe (BS x 64, rope'd)
// one wave per row, 4 rows per block
// ---------------------------------------------------------------------------
__global__ __launch_bounds__(256) void kv_norm_rope(const float* __restrict__ kvr,
                                                    const float* __restrict__ w,
                                                    const float* __restrict__ cosT,
                                                    const float* __restrict__ sinT,
                                                    float* __restrict__ kvn,
                                                    float* __restrict__ kpe)
{
    const int bs   = blockIdx.x * 4 + (threadIdx.x >> 6);
    const int lane = threadIdx.x & 63;
    const int s    = bs & (S_ - 1);
    const float* row = kvr + bs * 576;

    float v[8];
    float ss = 0.f;
#pragma unroll
    for (int j = 0; j < 8; j++) { v[j] = row[lane + 64*j]; ss += v[j]*v[j]; }
#pragma unroll
    for (int off = 32; off >= 1; off >>= 1) ss += __shfl_xor(ss, off);
    const float rs = rsqrtf(ss * (1.0f/512.0f) + 1e-6f);

    float* orow = kvn + bs * 512;
#pragma unroll
    for (int j = 0; j < 8; j++) orow[lane + 64*j] = v[j] * rs * w[lane + 64*j];

    if (lane < 32) {
        float xr = row[512 + 2*lane], xi = row[512 + 2*lane + 1];
        float c  = cosT[s*32 + lane], sn = sinT[s*32 + lane];
        kpe[bs*64 + 2*lane]     = xr*c - xi*sn;
        kpe[bs*64 + 2*lane + 1] = xr*sn + xi*c;
    }
}

// ---------------------------------------------------------------------------
// Fused attention: per block = (b, h, 32 query rows).
// thread (i0=tid>>4, c0=tid&15) owns rows r0=i0, r1=i0+16 and a c-slice:
//   score dim 576 sliced as [pe: 4c0..4c0+3 | abs: 32c0..32c0+31]
//   value dim 512 sliced as [32c0..32c0+31]
// Scores reduced across the 16 c0-lanes by __shfl_xor butterfly -> softmax is
// fully thread-local (replicated). Keys staged 16/iter in LDS (37 KB).
// q_pe rope + scale fused; q_abs = q_nope @ wb_h[:128] fused (qn staged in LDS);
// V-proj (o @ wb_h[128:]^T) fused in epilogue via butterfly.
// ---------------------------------------------------------------------------
__global__ __launch_bounds__(256) void attn_kernel(const float* __restrict__ q,
                                                   const float* __restrict__ kvn,
                                                   const float* __restrict__ kpe,
                                                   const float* __restrict__ cosT,
                                                   const float* __restrict__ sinT,
                                                   const float* __restrict__ wkv_b,
                                                   float* __restrict__ ov)
{
    const int q0 = blockIdx.x * 32;
    const int h  = blockIdx.y;
    const int b  = blockIdx.z;
    const int tid = threadIdx.x;
    const int i0 = tid >> 4;
    const int c0 = tid & 15;
    const int r0 = i0, r1 = i0 + 16;
    const float scale = 0.07216878364870323f;   // (NOPE+ROPE)^-0.5 = 192^-0.5

    __shared__ float kt[16][580];               // key tile: [pe 64 | kvn 512], 37.1 KB
    float* qn = &kt[0][0];                      // phase-0 scratch: [32][132] q_nope

    const int sA = q0 + r0;
    const int sB = q0 + r1;
    const int rowA = b*S_ + sA;
    const int rowB = b*S_ + sB;

    // ---- phase 0a: load q_pe slice, rope, scale (kept in registers) ----
    float4 qpeA, qpeB;
    {
        float4 pa = *(const float4*)(q + rowA*3072 + h*192 + 128 + 4*c0);
        float4 pb = *(const float4*)(q + rowB*3072 + h*192 + 128 + 4*c0);
        const int p0i = 2*c0, p1i = 2*c0 + 1;
        float ca0 = cosT[sA*32 + p0i], sa0 = sinT[sA*32 + p0i];
        float ca1 = cosT[sA*32 + p1i], sa1 = sinT[sA*32 + p1i];
        float cb0 = cosT[sB*32 + p0i], sb0 = sinT[sB*32 + p0i];
        float cb1 = cosT[sB*32 + p1i], sb1 = sinT[sB*32 + p1i];
        qpeA.x = (pa.x*ca0 - pa.y*sa0)*scale;
        qpeA.y = (pa.x*sa0 + pa.y*ca0)*scale;
        qpeA.z = (pa.z*ca1 - pa.w*sa1)*scale;
        qpeA.w = (pa.z*sa1 + pa.w*ca1)*scale;
        qpeB.x = (pb.x*cb0 - pb.y*sb0)*scale;
        qpeB.y = (pb.x*sb0 + pb.y*cb0)*scale;
        qpeB.z = (pb.z*cb1 - pb.w*sb1)*scale;
        qpeB.w = (pb.z*sb1 + pb.w*cb1)*scale;
    }

    // ---- phase 0b: stage q_nope (32x128) in LDS, compute q_abs slice ----
    for (int u = tid; u < 32*32; u += 256) {
        int r = u >> 5, cc = u & 31;
        *(float4*)(qn + r*132 + 4*cc) =
            *(const float4*)(q + (b*S_ + q0 + r)*3072 + h*192 + 4*cc);
    }
    __syncthreads();

    float4 qaA[8], qaB[8];
#pragma unroll
    for (int t = 0; t < 8; t++) {
        qaA[t] = make_float4(0.f,0.f,0.f,0.f);
        qaB[t] = make_float4(0.f,0.f,0.f,0.f);
    }
    const float* wbh = wkv_b + h*(256*512);
    for (int d = 0; d < 128; d++) {
        float a  = qn[r0*132 + d];
        float bq = qn[r1*132 + d];
        const float4* wr = (const float4*)(wbh + d*512 + c0*32);
#pragma unroll
        for (int t = 0; t < 8; t++) {
            float4 w = wr[t];
            qaA[t].x += a*w.x;  qaA[t].y += a*w.y;  qaA[t].z += a*w.z;  qaA[t].w += a*w.w;
            qaB[t].x += bq*w.x; qaB[t].y += bq*w.y; qaB[t].z += bq*w.z; qaB[t].w += bq*w.w;
        }
    }
#pragma unroll
    for (int t = 0; t < 8; t++) {
        qaA[t].x *= scale; qaA[t].y *= scale; qaA[t].z *= scale; qaA[t].w *= scale;
        qaB[t].x *= scale; qaB[t].y *= scale; qaB[t].z *= scale; qaB[t].w *= scale;
    }
    __syncthreads();   // qn scratch is about to become kt

    // ---- flash main loop over key tiles of 16 ----
    float4 oA[8], oB[8];
#pragma unroll
    for (int t = 0; t < 8; t++) {
        oA[t] = make_float4(0.f,0.f,0.f,0.f);
        oB[t] = make_float4(0.f,0.f,0.f,0.f);
    }
    float mA = -1e30f, mB = -1e30f, lA = 0.f, lB = 0.f;

    for (int t0 = 0; t0 <= q0 + 31; t0 += 16) {
        // stage 16 keys: row = [pe(64) | kvn(512)], coalesced float4
        for (int u = tid; u < 16*144; u += 256) {
            int j = u / 144, cc = u - j*144;
            int sk = b*S_ + t0 + j;
            float4 v;
            if (cc < 16) v = *(const float4*)(kpe + sk*64  + 4*cc);
            else         v = *(const float4*)(kvn + sk*512 + 4*(cc-16));
            *(float4*)(&kt[j][4*cc]) = v;
        }
        __syncthreads();

        float pA[16], pB[16];
#pragma unroll
        for (int j = 0; j < 16; j++) {
            const float4* kr = (const float4*)&kt[j][0];
            float4 kp = kr[c0];
            float a0 = qpeA.x*kp.x + qpeA.y*kp.y + qpeA.z*kp.z + qpeA.w*kp.w;
            float a1 = qpeB.x*kp.x + qpeB.y*kp.y + qpeB.z*kp.z + qpeB.w*kp.w;
#pragma unroll
            for (int t = 0; t < 8; t++) {
                float4 kv = kr[16 + c0*8 + t];
                a0 += qaA[t].x*kv.x + qaA[t].y*kv.y + qaA[t].z*kv.z + qaA[t].w*kv.w;
                a1 += qaB[t].x*kv.x + qaB[t].y*kv.y + qaB[t].z*kv.z + qaB[t].w*kv.w;
            }
#pragma unroll
            for (int off = 8; off >= 1; off >>= 1) {
                a0 += __shfl_xor(a0, off, 16);
                a1 += __shfl_xor(a1, off, 16);
            }
            int jg = t0 + j;
            pA[j] = (jg <= sA) ? a0 : -1e30f;
            pB[j] = (jg <= sB) ? a1 : -1e30f;
        }

        // online softmax (thread-local; values replicated across the 16 lanes)
        float mnA = mA, mnB = mB;
#pragma unroll
        for (int j = 0; j < 16; j++) { mnA = fmaxf(mnA, pA[j]); mnB = fmaxf(mnB, pB[j]); }
        float alA = __expf(mA - mnA), alB = __expf(mB - mnB);
        mA = mnA; mB = mnB;
        lA *= alA; lB *= alB;
#pragma unroll
        for (int t = 0; t < 8; t++) {
            oA[t].x *= alA; oA[t].y *= alA; oA[t].z *= alA; oA[t].w *= alA;
            oB[t].x *= alB; oB[t].y *= alB; oB[t].z *= alB; oB[t].w *= alB;
        }
#pragma unroll
        for (int j = 0; j < 16; j++) {
            pA[j] = __expf(pA[j] - mA); lA += pA[j];
            pB[j] = __expf(pB[j] - mB); lB += pB[j];
        }

        // o += p * V   (V = kvn part of kt)
#pragma unroll
        for (int j = 0; j < 16; j++) {
            const float4* kr = (const float4*)&kt[j][64];
            float pa = pA[j], pb = pB[j];
#pragma unroll
            for (int t = 0; t < 8; t++) {
                float4 kv = kr[c0*8 + t];
                oA[t].x += pa*kv.x; oA[t].y += pa*kv.y; oA[t].z += pa*kv.z; oA[t].w += pa*kv.w;
                oB[t].x += pb*kv.x; oB[t].y += pb*kv.y; oB[t].z += pb*kv.z; oB[t].w += pb*kv.w;
            }
        }
        __syncthreads();
    }

    const float rlA = 1.f/lA, rlB = 1.f/lB;
#pragma unroll
    for (int t = 0; t < 8; t++) {
        oA[t].x *= rlA; oA[t].y *= rlA; oA[t].z *= rlA; oA[t].w *= rlA;
        oB[t].x *= rlB; oB[t].y *= rlB; oB[t].z *= rlB; oB[t].w *= rlB;
    }

    // ---- epilogue: o_v[r][dv] = sum_c o[r][c] * wb_h[128+dv][c] ----
    const float* wbv = wkv_b + h*(256*512) + 128*512;
#pragma unroll 1
    for (int kk = 0; kk < 8; kk++) {
        float a0 = 0.f, a1 = 0.f;
#pragma unroll
        for (int dd = 0; dd < 16; dd++) {
            int dv = kk*16 + dd;
            const float4* wr = (const float4*)(wbv + dv*512 + c0*32);
            float p0 = 0.f, p1 = 0.f;
#pragma unroll
            for (int t = 0; t < 8; t++) {
                float4 w = wr[t];
                p0 += oA[t].x*w.x + oA[t].y*w.y + oA[t].z*w.z + oA[t].w*w.w;
                p1 += oB[t].x*w.x + oB[t].y*w.y + oB[t].z*w.z + oB[t].w*w.w;
            }
#pragma unroll
            for (int off = 8; off >= 1; off >>= 1) {
                p0 += __shfl_xor(p0, off, 16);
                p1 += __shfl_xor(p1, off, 16);
            }
            if (dd == c0) { a0 = p0; a1 = p1; }
        }
        ov[rowA*2048 + h*128 + kk*16 + c0] = a0;
        ov[rowB*2048 + h*128 + kk*16 + c0] = a1;
    }
}

// ---------------------------------------------------------------------------
extern "C" void kernel_launch(void* const* d_in, const int* in_sizes, int n_in,
                              void* d_out, int out_size, void* d_ws, size_t ws_size,
                              hipStream_t stream) {
    const float* x     = (const float*)d_in[0];
    const float* cosT  = (const float*)d_in[1];
    const float* sinT  = (const float*)d_in[2];
    // d_in[3] mask: unused (causality applied directly)
    const float* wq    = (const float*)d_in[4];
    const float* wkv_a = (const float*)d_in[5];
    const float* kvw   = (const float*)d_in[6];
    const float* wkv_b = (const float*)d_in[7];
    const float* wo    = (const float*)d_in[8];
    float* out = (float*)d_out;

    // workspace layout (floats), total 25,690,112 f32 = 102.8 MB
    float* q   = (float*)d_ws;            // 4096 x 3072
    float* kvr = q   + 12582912;          // 4096 x 576
    float* kvn = kvr + 2359296;           // 4096 x 512
    float* kpe = kvn + 2097152;           // 4096 x 64
    float* ov  = kpe + 262144;            // 4096 x 2048

    dim3 blk(256);
    // q = x @ wq^T            (4096 x 3072, K=2048)
    gemm_nt<<<dim3(3072/64, 4096/64), blk, 0, stream>>>(x, wq, q, 4096, 3072, 2048, 2048, 2048, 3072);
    // kvr = x @ wkv_a^T       (4096 x 576, K=2048)
    gemm_nt<<<dim3(576/64, 4096/64), blk, 0, stream>>>(x, wkv_a, kvr, 4096, 576, 2048, 2048, 2048, 576);
    // kvn = rmsnorm(kvr[:, :512]) * w ; kpe = rope(kvr[:, 512:])
    kv_norm_rope<<<dim3(4096/4), blk, 0, stream>>>(kvr, kvw, cosT, sinT, kvn, kpe);
    // fused rope(q_pe) + q_abs + flash attention + V-proj -> ov (4096 x 2048)
    attn_kernel<<<dim3(S_/32, H_, B_), blk, 0, stream>>>(q, kvn, kpe, cosT, sinT, wkv_b, ov);
    // out = ov @ wo^T         (4096 x 2048, K=2048)
    gemm_nt<<<dim3(2048/64, 4096/64), blk, 0, stream>>>(ov, wo, out, 4096, 2048, 2048, 2048, 2048, 2048);
}

// Round 2
// 18918.141 us; speedup vs baseline: 1.0885x; 1.0885x over previous
//
#include <hip/hip_runtime.h>
#include <hip/hip_bf16.h>

// MLA forward, round 2: attention bank-conflict fix + bf16 key tile.
// B=2 S=2048 D=2048 H=16 NOPE=128 ROPE=64 V=128 C=512
#define B_ 2
#define S_ 2048
#define D_ 2048
#define H_ 16

typedef unsigned short ushort_t;
typedef unsigned int uint_t;

__device__ __forceinline__ float2 bfx2(uint_t u) {
    // u = two bf16 (lo = element 0, hi = element 1) -> two f32
    float lo = __uint_as_float(u << 16);
    float hi = __uint_as_float(u & 0xffff0000u);
    return make_float2(lo, hi);
}

// ---------------------------------------------------------------------------
// Generic f32 GEMM:  C[M,N] = A[M,K] @ B[N,K]^T  (unchanged from round 1)
// ---------------------------------------------------------------------------
__global__ __launch_bounds__(256) void gemm_nt(const float* __restrict__ A,
                                               const float* __restrict__ Bm,
                                               float* __restrict__ Cm,
                                               int M, int N, int K,
                                               int lda, int ldb, int ldc)
{
    __shared__ float As[16][68];
    __shared__ float Bs[16][68];
    const int tid = threadIdx.x;
    const int m0 = blockIdx.y * 64, n0 = blockIdx.x * 64;
    const int lr = tid >> 2;
    const int lc = (tid & 3) << 2;
    const int ty = tid >> 4, tx = tid & 15;
    const float* Ag = A  + (m0 + lr) * lda + lc;
    const float* Bg = Bm + (n0 + lr) * ldb + lc;

    float acc[4][4];
#pragma unroll
    for (int i = 0; i < 4; i++)
#pragma unroll
        for (int j = 0; j < 4; j++) acc[i][j] = 0.f;

    for (int k0 = 0; k0 < K; k0 += 16) {
        float4 av = *(const float4*)(Ag + k0);
        float4 bv = *(const float4*)(Bg + k0);
        __syncthreads();
        As[lc+0][lr] = av.x; As[lc+1][lr] = av.y; As[lc+2][lr] = av.z; As[lc+3][lr] = av.w;
        Bs[lc+0][lr] = bv.x; Bs[lc+1][lr] = bv.y; Bs[lc+2][lr] = bv.z; Bs[lc+3][lr] = bv.w;
        __syncthreads();
#pragma unroll
        for (int kk = 0; kk < 16; kk++) {
            float4 a = *(const float4*)&As[kk][ty*4];
            float4 b = *(const float4*)&Bs[kk][tx*4];
            acc[0][0] += a.x*b.x; acc[0][1] += a.x*b.y; acc[0][2] += a.x*b.z; acc[0][3] += a.x*b.w;
            acc[1][0] += a.y*b.x; acc[1][1] += a.y*b.y; acc[1][2] += a.y*b.z; acc[1][3] += a.y*b.w;
            acc[2][0] += a.z*b.x; acc[2][1] += a.z*b.y; acc[2][2] += a.z*b.z; acc[2][3] += a.z*b.w;
            acc[3][0] += a.w*b.x; acc[3][1] += a.w*b.y; acc[3][2] += a.w*b.z; acc[3][3] += a.w*b.w;
        }
    }
#pragma unroll
    for (int i = 0; i < 4; i++) {
        float4 r; r.x = acc[i][0]; r.y = acc[i][1]; r.z = acc[i][2]; r.w = acc[i][3];
        *(float4*)(Cm + (m0 + ty*4 + i) * ldc + n0 + tx*4) = r;
    }
}

// ---------------------------------------------------------------------------
// kvr (BS x 576) -> kvn bf16 (BS x 512), kpe bf16 (BS x 64, rope'd)
// one wave per row, lane owns 8 consecutive elements.
// ---------------------------------------------------------------------------
__global__ __launch_bounds__(256) void kv_norm_rope(const float* __restrict__ kvr,
                                                    const float* __restrict__ w,
                                                    const float* __restrict__ cosT,
                                                    const float* __restrict__ sinT,
                                                    ushort_t* __restrict__ kvnb,
                                                    ushort_t* __restrict__ kpeb)
{
    const int bs   = blockIdx.x * 4 + (threadIdx.x >> 6);
    const int lane = threadIdx.x & 63;
    const int s    = bs & (S_ - 1);
    const float* row = kvr + bs * 576;

    float4 v0 = *(const float4*)(row + lane*8);
    float4 v1 = *(const float4*)(row + lane*8 + 4);
    float ss = v0.x*v0.x + v0.y*v0.y + v0.z*v0.z + v0.w*v0.w
             + v1.x*v1.x + v1.y*v1.y + v1.z*v1.z + v1.w*v1.w;
#pragma unroll
    for (int off = 32; off >= 1; off >>= 1) ss += __shfl_xor(ss, off);
    const float rs = rsqrtf(ss * (1.0f/512.0f) + 1e-6f);

    float4 w0 = *(const float4*)(w + lane*8);
    float4 w1 = *(const float4*)(w + lane*8 + 4);
    float o[8];
    o[0] = v0.x*rs*w0.x; o[1] = v0.y*rs*w0.y; o[2] = v0.z*rs*w0.z; o[3] = v0.w*rs*w0.w;
    o[4] = v1.x*rs*w1.x; o[5] = v1.y*rs*w1.y; o[6] = v1.z*rs*w1.z; o[7] = v1.w*rs*w1.w;
    uint_t pk[4];
#pragma unroll
    for (int p = 0; p < 4; p++) {
        __hip_bfloat16 blo = __float2bfloat16(o[2*p]);
        __hip_bfloat16 bhi = __float2bfloat16(o[2*p+1]);
        pk[p] = (uint_t)(*(ushort_t*)&blo) | ((uint_t)(*(ushort_t*)&bhi) << 16);
    }
    *(uint4*)(kvnb + bs*512 + lane*8) = make_uint4(pk[0], pk[1], pk[2], pk[3]);

    if (lane < 32) {
        float xr = row[512 + 2*lane], xi = row[512 + 2*lane + 1];
        float c  = cosT[s*32 + lane], sn = sinT[s*32 + lane];
        float yr = xr*c - xi*sn, yi = xr*sn + xi*c;
        __hip_bfloat16 blo = __float2bfloat16(yr);
        __hip_bfloat16 bhi = __float2bfloat16(yi);
        uint_t pv = (uint_t)(*(ushort_t*)&blo) | ((uint_t)(*(ushort_t*)&bhi) << 16);
        *(uint_t*)(kpeb + bs*64 + 2*lane) = pv;
    }
}

// ---------------------------------------------------------------------------
// Fused attention, conflict-free interleaved slicing + bf16 key tile.
// thread (i0=tid>>4, c0=tid&15) owns rows r0=i0, r1=i0+16 and slices:
//   pe dim 64:      elements 4*c0 .. 4*c0+3
//   abs/val dim 512: elements {128*t + 8*c0 + e}, t=0..3, e=0..7
// -> LDS lane addresses are consecutive 16B chunks (2-way max = free),
//    global wb/wbv reads are coalesced (16 lanes x 32B contiguous).
// Key tile: 16 keys x (pe 64 | kv 512) bf16, row stride 584 (+8 pad) = 18.7 KB.
// ---------------------------------------------------------------------------
__global__ __launch_bounds__(256) void attn_kernel(const float* __restrict__ q,
                                                   const ushort_t* __restrict__ kvnb,
                                                   const ushort_t* __restrict__ kpeb,
                                                   const float* __restrict__ cosT,
                                                   const float* __restrict__ sinT,
                                                   const float* __restrict__ wkv_b,
                                                   float* __restrict__ ov)
{
    const int q0 = blockIdx.x * 32;
    const int h  = blockIdx.y;
    const int b  = blockIdx.z;
    const int tid = threadIdx.x;
    const int i0 = tid >> 4;
    const int c0 = tid & 15;
    const int r0 = i0, r1 = i0 + 16;
    const float scale = 0.07216878364870323f;   // 192^-0.5

    __shared__ __align__(16) ushort_t kts[16 * 584];   // 18688 B
    float* qn = (float*)kts;                           // phase-0 overlay: 32*132*4 = 16896 B

    const int sA = q0 + r0;
    const int sB = q0 + r1;
    const int rowA = b*S_ + sA;
    const int rowB = b*S_ + sB;

    // ---- phase 0a: q_pe slice (elements 4c0..4c0+3), rope, scale ----
    float qpeA[4], qpeB[4];
    {
        float4 pa = *(const float4*)(q + rowA*3072 + h*192 + 128 + 4*c0);
        float4 pb = *(const float4*)(q + rowB*3072 + h*192 + 128 + 4*c0);
        const int p0i = 2*c0, p1i = 2*c0 + 1;
        float ca0 = cosT[sA*32 + p0i], sa0 = sinT[sA*32 + p0i];
        float ca1 = cosT[sA*32 + p1i], sa1 = sinT[sA*32 + p1i];
        float cb0 = cosT[sB*32 + p0i], sb0 = sinT[sB*32 + p0i];
        float cb1 = cosT[sB*32 + p1i], sb1 = sinT[sB*32 + p1i];
        qpeA[0] = (pa.x*ca0 - pa.y*sa0)*scale;
        qpeA[1] = (pa.x*sa0 + pa.y*ca0)*scale;
        qpeA[2] = (pa.z*ca1 - pa.w*sa1)*scale;
        qpeA[3] = (pa.z*sa1 + pa.w*ca1)*scale;
        qpeB[0] = (pb.x*cb0 - pb.y*sb0)*scale;
        qpeB[1] = (pb.x*sb0 + pb.y*cb0)*scale;
        qpeB[2] = (pb.z*cb1 - pb.w*sb1)*scale;
        qpeB[3] = (pb.z*sb1 + pb.w*cb1)*scale;
    }

    // ---- phase 0b: stage q_nope (32x128 f32) in LDS, compute q_abs slices ----
    for (int u = tid; u < 32*32; u += 256) {
        int r = u >> 5, cc = u & 31;
        *(float4*)(qn + r*132 + 4*cc) =
            *(const float4*)(q + (b*S_ + q0 + r)*3072 + h*192 + 4*cc);
    }
    __syncthreads();

    float qaA[4][8], qaB[4][8];
#pragma unroll
    for (int t = 0; t < 4; t++)
#pragma unroll
        for (int e = 0; e < 8; e++) { qaA[t][e] = 0.f; qaB[t][e] = 0.f; }

    const float* wbh = wkv_b + h*(256*512);
    for (int d = 0; d < 128; d++) {
        float a  = qn[r0*132 + d];
        float bq = qn[r1*132 + d];
        const float* wr = wbh + d*512 + 8*c0;
#pragma unroll
        for (int t = 0; t < 4; t++) {
            float4 wA = *(const float4*)(wr + 128*t);
            float4 wB = *(const float4*)(wr + 128*t + 4);
            qaA[t][0] += a*wA.x;  qaA[t][1] += a*wA.y;  qaA[t][2] += a*wA.z;  qaA[t][3] += a*wA.w;
            qaA[t][4] += a*wB.x;  qaA[t][5] += a*wB.y;  qaA[t][6] += a*wB.z;  qaA[t][7] += a*wB.w;
            qaB[t][0] += bq*wA.x; qaB[t][1] += bq*wA.y; qaB[t][2] += bq*wA.z; qaB[t][3] += bq*wA.w;
            qaB[t][4] += bq*wB.x; qaB[t][5] += bq*wB.y; qaB[t][6] += bq*wB.z; qaB[t][7] += bq*wB.w;
        }
    }
#pragma unroll
    for (int t = 0; t < 4; t++)
#pragma unroll
        for (int e = 0; e < 8; e++) { qaA[t][e] *= scale; qaB[t][e] *= scale; }
    __syncthreads();   // qn overlay becomes kts

    // ---- flash main loop over key tiles of 16 ----
    float oA[4][8], oB[4][8];
#pragma unroll
    for (int t = 0; t < 4; t++)
#pragma unroll
        for (int e = 0; e < 8; e++) { oA[t][e] = 0.f; oB[t][e] = 0.f; }
    float mA = -1e30f, mB = -1e30f, lA = 0.f, lB = 0.f;

    for (int t0 = 0; t0 <= q0 + 31; t0 += 16) {
        // stage 16 keys bf16: row = [pe(64) | kvn(512) | pad(8)]
        for (int u = tid; u < 16*72; u += 256) {
            int j = u / 72, cc = u - j*72;
            int sk = b*S_ + t0 + j;
            const ushort_t* src = (cc < 8) ? (kpeb + sk*64 + 8*cc)
                                           : (kvnb + sk*512 + 8*(cc-8));
            *(uint4*)(kts + j*584 + 8*cc) = *(const uint4*)src;
        }
        __syncthreads();

        float pA[16], pB[16];
#pragma unroll
        for (int j = 0; j < 16; j++) {
            const ushort_t* kr = kts + j*584;
            uint2 pe = *(const uint2*)(kr + 4*c0);
            float2 pe01 = bfx2(pe.x), pe23 = bfx2(pe.y);
            float a0 = qpeA[0]*pe01.x + qpeA[1]*pe01.y + qpeA[2]*pe23.x + qpeA[3]*pe23.y;
            float a1 = qpeB[0]*pe01.x + qpeB[1]*pe01.y + qpeB[2]*pe23.x + qpeB[3]*pe23.y;
#pragma unroll
            for (int t = 0; t < 4; t++) {
                uint4 kv = *(const uint4*)(kr + 64 + 128*t + 8*c0);
                float2 f0 = bfx2(kv.x), f1 = bfx2(kv.y), f2 = bfx2(kv.z), f3 = bfx2(kv.w);
                a0 += qaA[t][0]*f0.x + qaA[t][1]*f0.y + qaA[t][2]*f1.x + qaA[t][3]*f1.y
                    + qaA[t][4]*f2.x + qaA[t][5]*f2.y + qaA[t][6]*f3.x + qaA[t][7]*f3.y;
                a1 += qaB[t][0]*f0.x + qaB[t][1]*f0.y + qaB[t][2]*f1.x + qaB[t][3]*f1.y
                    + qaB[t][4]*f2.x + qaB[t][5]*f2.y + qaB[t][6]*f3.x + qaB[t][7]*f3.y;
            }
#pragma unroll
            for (int off = 8; off >= 1; off >>= 1) {
                a0 += __shfl_xor(a0, off, 16);
                a1 += __shfl_xor(a1, off, 16);
            }
            int jg = t0 + j;
            pA[j] = (jg <= sA) ? a0 : -1e30f;
            pB[j] = (jg <= sB) ? a1 : -1e30f;
        }

        // online softmax (thread-local; replicated across the 16 c0-lanes)
        float mnA = mA, mnB = mB;
#pragma unroll
        for (int j = 0; j < 16; j++) { mnA = fmaxf(mnA, pA[j]); mnB = fmaxf(mnB, pB[j]); }
        float alA = __expf(mA - mnA), alB = __expf(mB - mnB);
        mA = mnA; mB = mnB;
        lA *= alA; lB *= alB;
#pragma unroll
        for (int t = 0; t < 4; t++)
#pragma unroll
            for (int e = 0; e < 8; e++) { oA[t][e] *= alA; oB[t][e] *= alB; }
#pragma unroll
        for (int j = 0; j < 16; j++) {
            pA[j] = __expf(pA[j] - mA); lA += pA[j];
            pB[j] = __expf(pB[j] - mB); lB += pB[j];
        }

        // o += p * V
#pragma unroll
        for (int j = 0; j < 16; j++) {
            const ushort_t* kr = kts + j*584 + 64;
            float pa = pA[j], pb = pB[j];
#pragma unroll
            for (int t = 0; t < 4; t++) {
                uint4 kv = *(const uint4*)(kr + 128*t + 8*c0);
                float2 f0 = bfx2(kv.x), f1 = bfx2(kv.y), f2 = bfx2(kv.z), f3 = bfx2(kv.w);
                oA[t][0] += pa*f0.x; oA[t][1] += pa*f0.y; oA[t][2] += pa*f1.x; oA[t][3] += pa*f1.y;
                oA[t][4] += pa*f2.x; oA[t][5] += pa*f2.y; oA[t][6] += pa*f3.x; oA[t][7] += pa*f3.y;
                oB[t][0] += pb*f0.x; oB[t][1] += pb*f0.y; oB[t][2] += pb*f1.x; oB[t][3] += pb*f1.y;
                oB[t][4] += pb*f2.x; oB[t][5] += pb*f2.y; oB[t][6] += pb*f3.x; oB[t][7] += pb*f3.y;
            }
        }
        __syncthreads();
    }

    const float rlA = 1.f/lA, rlB = 1.f/lB;
#pragma unroll
    for (int t = 0; t < 4; t++)
#pragma unroll
        for (int e = 0; e < 8; e++) { oA[t][e] *= rlA; oB[t][e] *= rlB; }

    // ---- epilogue: o_v[r][dv] = sum_c o[r][c] * wbv[dv][c] ----
    const float* wbv = wkv_b + h*(256*512) + 128*512;
#pragma unroll 1
    for (int kk = 0; kk < 8; kk++) {
        float a0 = 0.f, a1 = 0.f;
#pragma unroll
        for (int dd = 0; dd < 16; dd++) {
            int dv = kk*16 + dd;
            const float* wr = wbv + dv*512 + 8*c0;
            float p0 = 0.f, p1 = 0.f;
#pragma unroll
            for (int t = 0; t < 4; t++) {
                float4 wA = *(const float4*)(wr + 128*t);
                float4 wB = *(const float4*)(wr + 128*t + 4);
                p0 += oA[t][0]*wA.x + oA[t][1]*wA.y + oA[t][2]*wA.z + oA[t][3]*wA.w
                    + oA[t][4]*wB.x + oA[t][5]*wB.y + oA[t][6]*wB.z + oA[t][7]*wB.w;
                p1 += oB[t][0]*wA.x + oB[t][1]*wA.y + oB[t][2]*wA.z + oB[t][3]*wA.w
                    + oB[t][4]*wB.x + oB[t][5]*wB.y + oB[t][6]*wB.z + oB[t][7]*wB.w;
            }
#pragma unroll
            for (int off = 8; off >= 1; off >>= 1) {
                p0 += __shfl_xor(p0, off, 16);
                p1 += __shfl_xor(p1, off, 16);
            }
            if (dd == c0) { a0 = p0; a1 = p1; }
        }
        ov[rowA*2048 + h*128 + kk*16 + c0] = a0;
        ov[rowB*2048 + h*128 + kk*16 + c0] = a1;
    }
}

// ---------------------------------------------------------------------------
extern "C" void kernel_launch(void* const* d_in, const int* in_sizes, int n_in,
                              void* d_out, int out_size, void* d_ws, size_t ws_size,
                              hipStream_t stream) {
    const float* x     = (const float*)d_in[0];
    const float* cosT  = (const float*)d_in[1];
    const float* sinT  = (const float*)d_in[2];
    // d_in[3] mask: unused (causality applied directly)
    const float* wq    = (const float*)d_in[4];
    const float* wkv_a = (const float*)d_in[5];
    const float* kvw   = (const float*)d_in[6];
    const float* wkv_b = (const float*)d_in[7];
    const float* wo    = (const float*)d_in[8];
    float* out = (float*)d_out;

    // workspace layout: q f32 | kvr f32 | ov f32 | kvn bf16 | kpe bf16  (~98 MB)
    float* q   = (float*)d_ws;            // 4096 x 3072 f32
    float* kvr = q   + 12582912;          // 4096 x 576  f32
    float* ov  = kvr + 2359296;           // 4096 x 2048 f32
    ushort_t* kvnb = (ushort_t*)(ov + 8388608);   // 4096 x 512 bf16
    ushort_t* kpeb = kvnb + 2097152;              // 4096 x 64  bf16

    dim3 blk(256);
    gemm_nt<<<dim3(3072/64, 4096/64), blk, 0, stream>>>(x, wq, q, 4096, 3072, 2048, 2048, 2048, 3072);
    gemm_nt<<<dim3(576/64, 4096/64), blk, 0, stream>>>(x, wkv_a, kvr, 4096, 576, 2048, 2048, 2048, 576);
    kv_norm_rope<<<dim3(4096/4), blk, 0, stream>>>(kvr, kvw, cosT, sinT, kvnb, kpeb);
    attn_kernel<<<dim3(S_/32, H_, B_), blk, 0, stream>>>(q, kvnb, kpeb, cosT, sinT, wkv_b, ov);
    gemm_nt<<<dim3(2048/64, 4096/64), blk, 0, stream>>>(ov, wo, out, 4096, 2048, 2048, 2048, 2048, 2048);
}

// Round 3
// 5471.735 us; speedup vs baseline: 3.7634x; 3.4574x over previous
//
#include <hip/hip_runtime.h>
#include <hip/hip_bf16.h>

// MLA forward, round 3: MFMA flash attention (bf16), f32 GEMMs unchanged.
// B=2 S=2048 D=2048 H=16 NOPE=128 ROPE=64 V=128 C=512
#define B_ 2
#define S_ 2048
#define D_ 2048
#define H_ 16

typedef unsigned short ushort_t;
typedef unsigned int uint_t;
typedef __attribute__((ext_vector_type(8))) short bf16x8;
typedef __attribute__((ext_vector_type(4))) float f32x4;

__device__ __forceinline__ ushort_t f2bf(float f) {
    uint_t u = __float_as_uint(f);
    return (ushort_t)((u + 0x7fffu + ((u >> 16) & 1u)) >> 16);
}

// ---------------------------------------------------------------------------
// Generic f32 GEMM:  C[M,N] = A[M,K] @ B[N,K]^T  (unchanged)
// ---------------------------------------------------------------------------
__global__ __launch_bounds__(256) void gemm_nt(const float* __restrict__ A,
                                               const float* __restrict__ Bm,
                                               float* __restrict__ Cm,
                                               int M, int N, int K,
                                               int lda, int ldb, int ldc)
{
    __shared__ float As[16][68];
    __shared__ float Bs[16][68];
    const int tid = threadIdx.x;
    const int m0 = blockIdx.y * 64, n0 = blockIdx.x * 64;
    const int lr = tid >> 2;
    const int lc = (tid & 3) << 2;
    const int ty = tid >> 4, tx = tid & 15;
    const float* Ag = A  + (m0 + lr) * lda + lc;
    const float* Bg = Bm + (n0 + lr) * ldb + lc;

    float acc[4][4];
#pragma unroll
    for (int i = 0; i < 4; i++)
#pragma unroll
        for (int j = 0; j < 4; j++) acc[i][j] = 0.f;

    for (int k0 = 0; k0 < K; k0 += 16) {
        float4 av = *(const float4*)(Ag + k0);
        float4 bv = *(const float4*)(Bg + k0);
        __syncthreads();
        As[lc+0][lr] = av.x; As[lc+1][lr] = av.y; As[lc+2][lr] = av.z; As[lc+3][lr] = av.w;
        Bs[lc+0][lr] = bv.x; Bs[lc+1][lr] = bv.y; Bs[lc+2][lr] = bv.z; Bs[lc+3][lr] = bv.w;
        __syncthreads();
#pragma unroll
        for (int kk = 0; kk < 16; kk++) {
            float4 a = *(const float4*)&As[kk][ty*4];
            float4 b = *(const float4*)&Bs[kk][tx*4];
            acc[0][0] += a.x*b.x; acc[0][1] += a.x*b.y; acc[0][2] += a.x*b.z; acc[0][3] += a.x*b.w;
            acc[1][0] += a.y*b.x; acc[1][1] += a.y*b.y; acc[1][2] += a.y*b.z; acc[1][3] += a.y*b.w;
            acc[2][0] += a.z*b.x; acc[2][1] += a.z*b.y; acc[2][2] += a.z*b.z; acc[2][3] += a.z*b.w;
            acc[3][0] += a.w*b.x; acc[3][1] += a.w*b.y; acc[3][2] += a.w*b.z; acc[3][3] += a.w*b.w;
        }
    }
#pragma unroll
    for (int i = 0; i < 4; i++) {
        float4 r; r.x = acc[i][0]; r.y = acc[i][1]; r.z = acc[i][2]; r.w = acc[i][3];
        *(float4*)(Cm + (m0 + ty*4 + i) * ldc + n0 + tx*4) = r;
    }
}

// ---------------------------------------------------------------------------
// prep: wbkT[h][c][d] = bf16(wkv_b[h][d][c])   (d < 128)
//       wbvB[h][dv][c] = bf16(wkv_b[h][128+dv][c])
// ---------------------------------------------------------------------------
__global__ __launch_bounds__(256) void prep_wb(const float* __restrict__ wkv_b,
                                               ushort_t* __restrict__ wbkT,
                                               ushort_t* __restrict__ wbvB)
{
    int u = blockIdx.x * 256 + threadIdx.x;   // 0 .. 1048575
    {
        int h = u >> 16, rem = u & 65535, c = rem >> 7, d = rem & 127;
        wbkT[u] = f2bf(wkv_b[h*131072 + d*512 + c]);
    }
    {
        int h = u >> 16, rem = u & 65535;       // dv = rem>>9, c = rem&511
        wbvB[u] = f2bf(wkv_b[h*131072 + 65536 + rem]);
    }
}

// ---------------------------------------------------------------------------
// kvr (BS x 576) -> kvnb bf16 [bs][512], kvnT bf16 [b][c][t], kpeb bf16 [bs][64]
// ---------------------------------------------------------------------------
__global__ __launch_bounds__(256) void kv_norm_rope(const float* __restrict__ kvr,
                                                    const float* __restrict__ w,
                                                    const float* __restrict__ cosT,
                                                    const float* __restrict__ sinT,
                                                    ushort_t* __restrict__ kvnb,
                                                    ushort_t* __restrict__ kvnT,
                                                    ushort_t* __restrict__ kpeb)
{
    const int bs   = blockIdx.x * 4 + (threadIdx.x >> 6);
    const int lane = threadIdx.x & 63;
    const int s    = bs & (S_ - 1);
    const float* row = kvr + bs * 576;

    float4 v0 = *(const float4*)(row + lane*8);
    float4 v1 = *(const float4*)(row + lane*8 + 4);
    float ss = v0.x*v0.x + v0.y*v0.y + v0.z*v0.z + v0.w*v0.w
             + v1.x*v1.x + v1.y*v1.y + v1.z*v1.z + v1.w*v1.w;
#pragma unroll
    for (int off = 32; off >= 1; off >>= 1) ss += __shfl_xor(ss, off);
    const float rs = rsqrtf(ss * (1.0f/512.0f) + 1e-6f);

    float4 w0 = *(const float4*)(w + lane*8);
    float4 w1 = *(const float4*)(w + lane*8 + 4);
    float o[8];
    o[0] = v0.x*rs*w0.x; o[1] = v0.y*rs*w0.y; o[2] = v0.z*rs*w0.z; o[3] = v0.w*rs*w0.w;
    o[4] = v1.x*rs*w1.x; o[5] = v1.y*rs*w1.y; o[6] = v1.z*rs*w1.z; o[7] = v1.w*rs*w1.w;

    ushort_t pk[8];
#pragma unroll
    for (int p = 0; p < 8; p++) pk[p] = f2bf(o[p]);
    *(uint4*)(kvnb + (size_t)bs*512 + lane*8) = *(const uint4*)pk;

    // transposed copy kvnT[b][c][t]
    const int bb = bs >> 11, t = bs & 2047;
    ushort_t* base = kvnT + ((size_t)(bb*512 + lane*8))*2048 + t;
#pragma unroll
    for (int k = 0; k < 8; k++) base[k*2048] = pk[k];

    if (lane < 32) {
        float xr = row[512 + 2*lane], xi = row[512 + 2*lane + 1];
        float c  = cosT[s*32 + lane], sn = sinT[s*32 + lane];
        ushort_t p2[2] = { f2bf(xr*c - xi*sn), f2bf(xr*sn + xi*c) };
        *(uint_t*)(kpeb + (size_t)bs*64 + 2*lane) = *(const uint_t*)p2;
    }
}

// ---------------------------------------------------------------------------
// MFMA flash attention. Block = (b, h, 64 q-rows); 4 waves; wave owns 16 rows.
// Layouts (mfma_f32_16x16x32_bf16, verified):
//   A-frag: A[m=lane&15][k=quad*8+j]   C/D: D[row=quad*4+reg][col=lane&15]
// LDS 61952 B: kt 32x584 (37376) | vt 256x40 (20480) | pt 64x32 (4096)
// overlays: qn(64x136)->vt, halfbuf(64x264)->kt (phase A / epilogue)
// ---------------------------------------------------------------------------
__global__ __launch_bounds__(256, 1) void attn_mfma(
    const float* __restrict__ q,
    const ushort_t* __restrict__ kvnb,
    const ushort_t* __restrict__ kpeb,
    const ushort_t* __restrict__ kvnT,
    const float* __restrict__ cosT,
    const float* __restrict__ sinT,
    const ushort_t* __restrict__ wbkT,
    const ushort_t* __restrict__ wbvB,
    float* __restrict__ ov)
{
    const int q0 = blockIdx.x * 64;
    const int h  = blockIdx.y;
    const int b  = blockIdx.z;
    const int tid  = threadIdx.x;
    const int wv   = tid >> 6;
    const int lane = tid & 63;
    const int l16  = lane & 15;
    const int quad = lane >> 4;
    const float scale = 0.07216878364870323f;   // 192^-0.5

    __shared__ __align__(16) ushort_t lds[30976];    // 61952 B
    ushort_t* kt = lds;             // 32 x 584
    ushort_t* vt = lds + 18688;     // 256 x 40
    ushort_t* pt = lds + 28928;     // 64 x 32

    const int mrow = wv*16 + l16;         // this lane's A-frag row (local i)
    const int irow = wv*16 + quad*4;      // this lane's C-layout row base
    const int sg   = q0 + mrow;           // global s for A-row

    // ===== phase A: build Q-frags (18 x bf16x8 in registers) =====
    ushort_t* qn = vt;                    // 64 x 136 bf16 q_nope
    for (int u = tid; u < 2048; u += 256) {
        int r = u >> 5, c4 = (u & 31) << 2;
        float4 v = *(const float4*)(q + (size_t)(b*S_ + q0 + r)*3072 + h*192 + c4);
        ushort_t pk[4] = { f2bf(v.x), f2bf(v.y), f2bf(v.z), f2bf(v.w) };
        *(uint2*)(qn + r*136 + c4) = *(const uint2*)pk;
    }
    __syncthreads();

    bf16x8 qf[18];
    bf16x8 qa[4];
#pragma unroll
    for (int ks = 0; ks < 4; ks++)
        qa[ks] = *(const bf16x8*)(qn + mrow*136 + ks*32 + quad*8);

    ushort_t* halfbuf = kt;               // 64 x 264
    const ushort_t* wbk_h = wbkT + h*65536;
#pragma unroll 1
    for (int half = 0; half < 2; half++) {
        f32x4 ab[16];
#pragma unroll
        for (int n = 0; n < 16; n++) ab[n] = (f32x4)(0.f);
#pragma unroll 1
        for (int n = 0; n < 16; n++) {
            const ushort_t* wp = wbk_h + (half*256 + n*16 + l16)*128 + quad*8;
#pragma unroll
            for (int ks = 0; ks < 4; ks++) {
                bf16x8 bw = *(const bf16x8*)(wp + ks*32);
                ab[n] = __builtin_amdgcn_mfma_f32_16x16x32_bf16(qa[ks], bw, ab[n], 0, 0, 0);
            }
        }
#pragma unroll
        for (int n = 0; n < 16; n++)
#pragma unroll
            for (int r = 0; r < 4; r++)
                halfbuf[(irow + r)*264 + n*16 + l16] = f2bf(ab[n][r] * scale);
        // in-wave round trip (each wave reads only its own 16 rows)
#pragma unroll
        for (int ks = 0; ks < 8; ks++)
            qf[half*8 + ks] = *(const bf16x8*)(halfbuf + mrow*264 + ks*32 + quad*8);
    }

    // pe part -> qf[16], qf[17]
#pragma unroll
    for (int ks = 16; ks < 18; ks++) {
        int off = (ks - 16)*32 + quad*8;
        const float* qp = q + (size_t)(b*S_ + sg)*3072 + h*192 + 128 + off;
        float4 x0 = *(const float4*)qp;
        float4 x1 = *(const float4*)(qp + 4);
        float xs[8] = {x0.x, x0.y, x0.z, x0.w, x1.x, x1.y, x1.z, x1.w};
        ushort_t pk[8];
#pragma unroll
        for (int u2 = 0; u2 < 4; u2++) {
            int pi = (off >> 1) + u2;
            float c = cosT[sg*32 + pi], sn = sinT[sg*32 + pi];
            pk[2*u2]   = f2bf((xs[2*u2]*c  - xs[2*u2+1]*sn) * scale);
            pk[2*u2+1] = f2bf((xs[2*u2]*sn + xs[2*u2+1]*c ) * scale);
        }
        qf[ks] = *(const bf16x8*)pk;
    }
    __syncthreads();   // qn/halfbuf dead; main loop may overwrite

    // ===== flash main loop =====
    f32x4 o[32];
#pragma unroll
    for (int n = 0; n < 32; n++) o[n] = (f32x4)(0.f);
    float m[4] = {-1e30f, -1e30f, -1e30f, -1e30f};
    float l[4] = {0.f, 0.f, 0.f, 0.f};
    const int niter = (q0 >> 5) + 2;

#pragma unroll 1
    for (int it = 0; it < niter; it++) {
        const int t0 = it * 32;
        // stage kt: 32 keys x [kv512 | pe64], stride 584
        for (int u = tid; u < 2304; u += 256) {
            int j = u / 72, cc = u - j*72;
            const ushort_t* src = (cc < 64)
                ? (kvnb + (size_t)(b*S_ + t0 + j)*512 + cc*8)
                : (kpeb + (size_t)(b*S_ + t0 + j)*64 + (cc - 64)*8);
            *(uint4*)(kt + j*584 + cc*8) = *(const uint4*)src;
        }
        // stage vt half 0: c in [0,256)
        for (int u = tid; u < 1024; u += 256) {
            int c = u >> 2, part = u & 3;
            *(uint4*)(vt + c*40 + part*8) =
                *(const uint4*)(kvnT + (size_t)(b*512 + c)*2048 + t0 + part*8);
        }
        __syncthreads();   // B1

        // scores: 2 n-tiles x 18 k-steps
        f32x4 s0 = (f32x4)(0.f), s1 = (f32x4)(0.f);
#pragma unroll
        for (int ks = 0; ks < 18; ks++) {
            bf16x8 k0 = *(const bf16x8*)(kt + l16*584        + ks*32 + quad*8);
            bf16x8 k1 = *(const bf16x8*)(kt + (16 + l16)*584 + ks*32 + quad*8);
            s0 = __builtin_amdgcn_mfma_f32_16x16x32_bf16(qf[ks], k0, s0, 0, 0, 0);
            s1 = __builtin_amdgcn_mfma_f32_16x16x32_bf16(qf[ks], k1, s1, 0, 0, 0);
        }

        // mask + online softmax (C-layout; row = irow+r, cols t0+l16 / t0+16+l16)
        float p0[4], p1[4];
#pragma unroll
        for (int r = 0; r < 4; r++) {
            p0[r] = (t0 + l16      <= q0 + irow + r) ? s0[r] : -1e30f;
            p1[r] = (t0 + 16 + l16 <= q0 + irow + r) ? s1[r] : -1e30f;
        }
#pragma unroll
        for (int r = 0; r < 4; r++) {
            float v = fmaxf(p0[r], p1[r]);
            v = fmaxf(v, __shfl_xor(v, 1, 16));
            v = fmaxf(v, __shfl_xor(v, 2, 16));
            v = fmaxf(v, __shfl_xor(v, 4, 16));
            v = fmaxf(v, __shfl_xor(v, 8, 16));
            float mn = fmaxf(m[r], v);
            float al = __expf(m[r] - mn);
            m[r] = mn;
            p0[r] = __expf(p0[r] - mn);
            p1[r] = __expf(p1[r] - mn);
            float rsum = p0[r] + p1[r];
            rsum += __shfl_xor(rsum, 1, 16);
            rsum += __shfl_xor(rsum, 2, 16);
            rsum += __shfl_xor(rsum, 4, 16);
            rsum += __shfl_xor(rsum, 8, 16);
            l[r] = l[r]*al + rsum;
#pragma unroll
            for (int n = 0; n < 32; n++) o[n][r] *= al;
        }

        // P -> LDS (C-layout scatter), read back as A-frag (own rows only)
#pragma unroll
        for (int r = 0; r < 4; r++) {
            pt[(irow + r)*32 + l16]      = f2bf(p0[r]);
            pt[(irow + r)*32 + 16 + l16] = f2bf(p1[r]);
        }
        bf16x8 ap = *(const bf16x8*)(pt + mrow*32 + quad*8);

        // PV half 0 (c 0..255)
#pragma unroll
        for (int n = 0; n < 16; n++) {
            bf16x8 bv = *(const bf16x8*)(vt + (n*16 + l16)*40 + quad*8);
            o[n] = __builtin_amdgcn_mfma_f32_16x16x32_bf16(ap, bv, o[n], 0, 0, 0);
        }
        __syncthreads();   // B2: all waves done with vt half 0

        // stage vt half 1: c in [256,512)
        for (int u = tid; u < 1024; u += 256) {
            int c = u >> 2, part = u & 3;
            *(uint4*)(vt + c*40 + part*8) =
                *(const uint4*)(kvnT + (size_t)(b*512 + 256 + c)*2048 + t0 + part*8);
        }
        __syncthreads();   // B3

#pragma unroll
        for (int n = 0; n < 16; n++) {
            bf16x8 bv = *(const bf16x8*)(vt + (n*16 + l16)*40 + quad*8);
            o[16 + n] = __builtin_amdgcn_mfma_f32_16x16x32_bf16(ap, bv, o[16 + n], 0, 0, 0);
        }
        __syncthreads();   // B4: protect kt/vt/pt for next iteration
    }

    // ===== epilogue: ov[i][dv] = (o[i][c]/l[i]) . wbv[dv][c]  (MFMA, k-halves) =====
    float rl[4];
#pragma unroll
    for (int r = 0; r < 4; r++) rl[r] = 1.f / l[r];

    const ushort_t* wbv_h = wbvB + h*65536;
    f32x4 acc2[8];
#pragma unroll
    for (int n = 0; n < 8; n++) acc2[n] = (f32x4)(0.f);

#pragma unroll 1
    for (int half = 0; half < 2; half++) {
#pragma unroll
        for (int n = 0; n < 16; n++)
#pragma unroll
            for (int r = 0; r < 4; r++)
                halfbuf[(irow + r)*264 + n*16 + l16] = f2bf(o[half*16 + n][r] * rl[r]);
#pragma unroll 1
        for (int ks = 0; ks < 8; ks++) {
            bf16x8 af = *(const bf16x8*)(halfbuf + mrow*264 + ks*32 + quad*8);
#pragma unroll
            for (int n = 0; n < 8; n++) {
                bf16x8 bw = *(const bf16x8*)(wbv_h + (n*16 + l16)*512 + half*256 + ks*32 + quad*8);
                acc2[n] = __builtin_amdgcn_mfma_f32_16x16x32_bf16(af, bw, acc2[n], 0, 0, 0);
            }
        }
    }

#pragma unroll
    for (int n = 0; n < 8; n++)
#pragma unroll
        for (int r = 0; r < 4; r++)
            ov[(size_t)(b*S_ + q0 + irow + r)*2048 + h*128 + n*16 + l16] = acc2[n][r];
}

// ---------------------------------------------------------------------------
extern "C" void kernel_launch(void* const* d_in, const int* in_sizes, int n_in,
                              void* d_out, int out_size, void* d_ws, size_t ws_size,
                              hipStream_t stream) {
    const float* x     = (const float*)d_in[0];
    const float* cosT  = (const float*)d_in[1];
    const float* sinT  = (const float*)d_in[2];
    // d_in[3] mask: unused (causality applied directly)
    const float* wq    = (const float*)d_in[4];
    const float* wkv_a = (const float*)d_in[5];
    const float* kvw   = (const float*)d_in[6];
    const float* wkv_b = (const float*)d_in[7];
    const float* wo    = (const float*)d_in[8];
    float* out = (float*)d_out;

    // workspace (92.5 MB):
    float* q   = (float*)d_ws;                     // 4096 x 3072 f32
    float* ov  = q + 12582912;                     // 4096 x 2048 f32
    float* kvr = ov;                               // 4096 x 576 f32 (aliases ov; dead before attn)
    ushort_t* kvnb = (ushort_t*)(ov + 8388608);    // 4096 x 512 bf16
    ushort_t* kpeb = kvnb + 2097152;               // 4096 x 64 bf16
    ushort_t* kvnT = kpeb + 262144;                // 2 x 512 x 2048 bf16
    ushort_t* wbkT = kvnT + 2097152;               // 16 x 512 x 128 bf16
    ushort_t* wbvB = wbkT + 1048576;               // 16 x 128 x 512 bf16

    dim3 blk(256);
    prep_wb<<<dim3(4096), blk, 0, stream>>>(wkv_b, wbkT, wbvB);
    gemm_nt<<<dim3(3072/64, 4096/64), blk, 0, stream>>>(x, wq, q, 4096, 3072, 2048, 2048, 2048, 3072);
    gemm_nt<<<dim3(576/64, 4096/64), blk, 0, stream>>>(x, wkv_a, kvr, 4096, 576, 2048, 2048, 2048, 576);
    kv_norm_rope<<<dim3(4096/4), blk, 0, stream>>>(kvr, kvw, cosT, sinT, kvnb, kvnT, kpeb);
    attn_mfma<<<dim3(S_/64, H_, B_), blk, 0, stream>>>(q, kvnb, kpeb, kvnT, cosT, sinT, wbkT, wbvB, ov);
    gemm_nt<<<dim3(2048/64, 4096/64), blk, 0, stream>>>(ov, wo, out, 4096, 2048, 2048, 2048, 2048, 2048);
}